// Round 13
// baseline (1882.236 us; speedup 1.0000x reference)
//
#include <hip/hip_runtime.h>
#include <math.h>

#define SEQ 256
#define BATCH 64
#define HID 1024
#define VOCAB 4000
#define H3 (3 * HID)
#define HSLICE (BATCH * HID)

typedef __attribute__((ext_vector_type(8))) short short8;
typedef __attribute__((ext_vector_type(4))) float f32x4;

__device__ inline unsigned short f2bf(float x) {
    unsigned int u = __builtin_bit_cast(unsigned int, x);
    unsigned int r = (u + 0x7fffu + ((u >> 16) & 1u)) >> 16;   // RNE
    return (unsigned short)r;
}
__device__ inline float bf2f(unsigned short h) {
    unsigned int u = ((unsigned int)h) << 16;
    return __builtin_bit_cast(float, u);
}

// ---------------------------------------------------------------------------
// Split f32 arrays into bf16 hi/lo pairs. h0 goes into slice 0 of the
// h-history (so the persistent kernel has no t==0 special case).
// ---------------------------------------------------------------------------
__global__ __launch_bounds__(256) void split_kernel(
    const float* __restrict__ W_hh, const float* __restrict__ W_out,
    const float* __restrict__ h0,
    unsigned short* __restrict__ whh_hi, unsigned short* __restrict__ whh_lo,
    unsigned short* __restrict__ wout_hi, unsigned short* __restrict__ wout_lo,
    unsigned short* __restrict__ h0_hi, unsigned short* __restrict__ h0_lo)
{
    const int NW = 3 * HID * HID;
    const int NO = VOCAB * HID;
    const int NH = BATCH * HID;
    const int total = NW + NO + NH;
    for (int i = blockIdx.x * blockDim.x + threadIdx.x; i < total;
         i += gridDim.x * blockDim.x) {
        const float* src; unsigned short *dh, *dl; int off;
        if (i < NW)           { src = W_hh;  dh = whh_hi;  dl = whh_lo;  off = i; }
        else if (i < NW + NO) { src = W_out; dh = wout_hi; dl = wout_lo; off = i - NW; }
        else                  { src = h0;    dh = h0_hi;   dl = h0_lo;   off = i - NW - NO; }
        float x = src[off];
        unsigned short hi = f2bf(x);
        dh[off] = hi;
        dl[off] = f2bf(x - bf2f(hi));
    }
}

// ---------------------------------------------------------------------------
// W_ih (3072 x 4000) -> W_ihT (4000 x 3072), 32x32 LDS tiles.
// ---------------------------------------------------------------------------
__global__ __launch_bounds__(256) void transpose_wih(
    const float* __restrict__ W_ih, float* __restrict__ W_ihT)
{
    __shared__ float tile[32][33];
    const int tx = threadIdx.x & 31;
    const int ty = threadIdx.x >> 5;          // 0..7
    const int r0 = blockIdx.y * 32;           // 3072-dim base
    const int c0 = blockIdx.x * 32;           // 4000-dim base
    #pragma unroll
    for (int k = 0; k < 4; ++k) {
        const int r = ty + k * 8;
        tile[r][tx] = W_ih[(size_t)(r0 + r) * VOCAB + c0 + tx];  // 4000%32==0
    }
    __syncthreads();
    #pragma unroll
    for (int k = 0; k < 4; ++k) {
        const int r = ty + k * 8;
        W_ihT[(size_t)(c0 + r) * H3 + r0 + tx] = tile[tx][r];
    }
}

__global__ void zero_barrier(int* b) {                    // 32768 ints (128 KB)
    b[blockIdx.x * 1024 + threadIdx.x] = 0;
}

// ---------------------------------------------------------------------------
// Persistent cooperative GRU: 256 blocks x 1024 threads (16 waves, 1/CU) —
// round-10 geometry (weights register-hoisted, 16-way K-split) with the
// barrier-#2 elimination:
//   - red[] parity-double-buffered (+pad 65 to rotate banks) -> no trailing
//     barrier needed for LDS reuse. t+2 reuse is ordered transitively by the
//     dataflow (consumers poll ALL 4 epilogue-wave flags of each producer).
//   - per-EPILOGUE-WAVE publish: each of the 4 epilogue waves WT-stores its
//     h rows (agent-scope packed u32, write-through to LLC), waits its OWN
//     vmcnt(0) (just its 2 stores), lane 0 stores flag[jt][mt][ew] = t+1.
//   - x_proj prefetch issues AFTER the flag publish (full step of slack).
// Consumer wave w polls 16 flags (4 producer j-tiles x 4 epilogue waves,
// lanes 0-15). Flags monotone; zeroed once per launch. ONE barrier per step.
// ---------------------------------------------------------------------------
__global__ __launch_bounds__(1024) void gru_persist(
    const unsigned short* __restrict__ whh_hi,
    const unsigned short* __restrict__ whh_lo,
    const float* __restrict__ W_ihT,
    const float* __restrict__ b_ih,
    const float* __restrict__ b_hh,
    const float* __restrict__ h0,
    const int* __restrict__ ids,
    unsigned short* ghi,                 // (SEQ+1) slices of 64x1024
    unsigned short* glo,
    float* hn_out,                       // d_out tail (64x1024)
    int* flag)                           // 1024 flags, stride 32 ints
{
    __shared__ f32x4 red[2][16][3][65];  // parity dbuf + bank-rotating pad

    const int tid = threadIdx.x;
    const int w   = tid >> 6;            // 0..15 (K-split)
    const int l   = tid & 63;
    const int bid = blockIdx.x;
    const int grp   = bid & 7;           // XCD (round-robin dispatch)
    const int local = bid >> 3;          // 0..31
    const int jt  = grp * 8 + (local >> 2);
    const int mt  = local & 3;
    const int j0  = jt * 16;
    const int m0  = mt * 16;
    const int col = l & 15, kg = l >> 4;

    const size_t arow   = (size_t)(m0 + col) * HID;
    const size_t brow_r = (size_t)(j0 + col) * HID;
    const size_t brow_z = (size_t)(HID + j0 + col) * HID;
    const size_t brow_n = (size_t)(2 * HID + j0 + col) * HID;
    const int kbase = w * 64 + kg * 8;

    // ---- hoist this wave's weight fragments into registers (48 VGPRs) ----
    short8 wr_h[2], wr_l[2], wz_h[2], wz_l[2], wn_h[2], wn_l[2];
    #pragma unroll
    for (int c = 0; c < 2; ++c) {
        const int ko = kbase + c * 32;
        wr_h[c] = *(const short8*)(whh_hi + brow_r + ko);
        wr_l[c] = *(const short8*)(whh_lo + brow_r + ko);
        wz_h[c] = *(const short8*)(whh_hi + brow_z + ko);
        wz_l[c] = *(const short8*)(whh_lo + brow_z + ko);
        wn_h[c] = *(const short8*)(whh_hi + brow_n + ko);
        wn_l[c] = *(const short8*)(whh_lo + brow_n + ko);
    }

    // epilogue persistent state: tid<256, 1 thread = 1 output (b, j)
    const int bi = (tid >> 4) & 15;
    const int cj = tid & 15;
    const int eb = m0 + bi, ej = j0 + cj;
    float hreg = 0.f, xr_n = 0.f, xz_n = 0.f, xn_n = 0.f;
    float bihr = 0.f, bihz = 0.f, bihn = 0.f;
    float bhhr = 0.f, bhhz = 0.f, bhhn = 0.f;
    if (tid < 256) {
        hreg = h0[(size_t)eb * HID + ej];
        bihr = b_ih[ej]; bihz = b_ih[HID + ej]; bihn = b_ih[2 * HID + ej];
        bhhr = b_hh[ej]; bhhz = b_hh[HID + ej]; bhhn = b_hh[2 * HID + ej];
        const int id0 = ids[eb * SEQ];
        const float* xrow = W_ihT + (size_t)id0 * H3;
        xr_n = xrow[ej]; xz_n = xrow[HID + ej]; xn_n = xrow[2 * HID + ej];
    }
    const int lane = ((bi & 15) >> 2) * 16 + cj;   // MFMA C-layout inverse
    const int reg  = bi & 3;

    // flags: ((jt*4 + mt)*4 + epilogue_wave) * 32
    const int myflag = ((jt * 4 + mt) * 4 + w) * 32;   // used by waves 0-3
    const int pollfl = (((4 * w + (l >> 2)) * 4 + mt) * 4 + (l & 3)) * 32;

    for (int t = 0; t < SEQ; ++t) {
        // ---- dataflow wait: 4 producer blocks x 4 epilogue waves ----
        if (t > 0) {
            if (l < 16) {
                while (__hip_atomic_load(&flag[pollfl], __ATOMIC_RELAXED,
                                         __HIP_MEMORY_SCOPE_AGENT) < t)
                    __builtin_amdgcn_s_sleep(1);
            }
            asm volatile("" ::: "memory");   // no load hoisting above polls
        }

        const unsigned short* ah = ghi + (size_t)t * HSLICE;   // h_{t-1}
        const unsigned short* al = glo + (size_t)t * HSLICE;

        f32x4 accr = {0.f, 0.f, 0.f, 0.f};
        f32x4 accz = {0.f, 0.f, 0.f, 0.f};
        f32x4 accn = {0.f, 0.f, 0.f, 0.f};

        #pragma unroll
        for (int c = 0; c < 2; ++c) {
            const int ko = kbase + c * 32;
            short8 a_h = *(const short8*)(ah + arow + ko);
            short8 a_l = *(const short8*)(al + arow + ko);

            accr = __builtin_amdgcn_mfma_f32_16x16x32_bf16(a_h, wr_h[c], accr, 0, 0, 0);
            accr = __builtin_amdgcn_mfma_f32_16x16x32_bf16(a_h, wr_l[c], accr, 0, 0, 0);
            accr = __builtin_amdgcn_mfma_f32_16x16x32_bf16(a_l, wr_h[c], accr, 0, 0, 0);

            accz = __builtin_amdgcn_mfma_f32_16x16x32_bf16(a_h, wz_h[c], accz, 0, 0, 0);
            accz = __builtin_amdgcn_mfma_f32_16x16x32_bf16(a_h, wz_l[c], accz, 0, 0, 0);
            accz = __builtin_amdgcn_mfma_f32_16x16x32_bf16(a_l, wz_h[c], accz, 0, 0, 0);

            accn = __builtin_amdgcn_mfma_f32_16x16x32_bf16(a_h, wn_h[c], accn, 0, 0, 0);
            accn = __builtin_amdgcn_mfma_f32_16x16x32_bf16(a_h, wn_l[c], accn, 0, 0, 0);
            accn = __builtin_amdgcn_mfma_f32_16x16x32_bf16(a_l, wn_h[c], accn, 0, 0, 0);
        }

        const int par = t & 1;
        red[par][w][0][l] = accr;
        red[par][w][1][l] = accz;
        red[par][w][2][l] = accn;
        __syncthreads();                 // the ONLY barrier this step

        if (tid < 256) {
            float sr = 0.f, sz = 0.f, sn = 0.f;
            #pragma unroll
            for (int kk = 0; kk < 16; ++kk) {
                sr += ((const float*)&red[par][kk][0][lane])[reg];
                sz += ((const float*)&red[par][kk][1][lane])[reg];
                sn += ((const float*)&red[par][kk][2][lane])[reg];
            }
            const float xr = xr_n + bihr;
            const float xz = xz_n + bihz;
            const float xn = xn_n + bihn;
            const float rg = 1.f / (1.f + expf(-(xr + sr + bhhr)));
            const float zg = 1.f / (1.f + expf(-(xz + sz + bhhz)));
            const float ng = tanhf(xn + rg * (sn + bhhn));
            hreg = (1.f - zg) * ng + zg * hreg;

            // ---- h store: packed u32, agent-scope write-through ----
            const unsigned short hh = f2bf(hreg);
            const unsigned short ll = f2bf(hreg - bf2f(hh));
            const unsigned int hh_n = (unsigned int)(unsigned short)
                __shfl_xor((int)hh, 1, 64);
            const unsigned int ll_n = (unsigned int)(unsigned short)
                __shfl_xor((int)ll, 1, 64);
            const size_t ho = (size_t)(t + 1) * HSLICE + (size_t)eb * HID + ej;
            if ((cj & 1) == 0) {
                const unsigned int hp = (unsigned int)hh | (hh_n << 16);
                const unsigned int lp = (unsigned int)ll | (ll_n << 16);
                __hip_atomic_store((unsigned int*)ghi + (ho >> 1), hp,
                                   __ATOMIC_RELAXED, __HIP_MEMORY_SCOPE_AGENT);
                __hip_atomic_store((unsigned int*)glo + (ho >> 1), lp,
                                   __ATOMIC_RELAXED, __HIP_MEMORY_SCOPE_AGENT);
            }
            // per-wave publish: wait own stores (at LLC), then own flag
            asm volatile("s_waitcnt vmcnt(0)" ::: "memory");
            if (l == 0) {
                __hip_atomic_store(&flag[myflag], t + 1, __ATOMIC_RELAXED,
                                   __HIP_MEMORY_SCOPE_AGENT);
            }
            // prefetch next x_proj row AFTER publish (full step of slack)
            if (t + 1 < SEQ) {
                const int id2 = ids[eb * SEQ + t + 1];
                const float* xrow = W_ihT + (size_t)id2 * H3;
                xr_n = xrow[ej]; xz_n = xrow[HID + ej]; xn_n = xrow[2 * HID + ej];
            } else {
                hn_out[(size_t)eb * HID + ej] = hreg;
            }
        }
        // no trailing barrier: red[] is parity-double-buffered; t+2 reuse is
        // ordered by the 2-hop flag dependency chain (see header comment).
    }
}

// ---------------------------------------------------------------------------
// Output GEMM, split-bf16 MFMA. 1D grid 4096 blocks, XCD-aware stripes.
// ---------------------------------------------------------------------------
__global__ __launch_bounds__(256) void out_gemm_mfma(
    const unsigned short* __restrict__ Ahi_g,  // 16384 x 1024
    const unsigned short* __restrict__ Alo_g,
    const unsigned short* __restrict__ Bhi_g,  // 4000 x 1024
    const unsigned short* __restrict__ Blo_g,
    const float* __restrict__ bias,
    float* __restrict__ C)
{
    constexpr int BM = 128, BK = 32, LDK = 40;
    __shared__ unsigned short Ah[BM * LDK], Al[BM * LDK];
    __shared__ unsigned short Bh[BM * LDK], Bl[BM * LDK];

    const int tid = threadIdx.x;
    const int l = tid & 63, w = tid >> 6;
    const int wr = w >> 1, wc = w & 1;
    const int col = l & 15, kg = l >> 4;
    const int bid = blockIdx.x;
    const int xcd = bid & 7;
    const int q   = bid >> 3;
    const int yb  = xcd * 4 + (q >> 7);       // 0..31 (n-tile)
    const int xb  = q & 127;                  // 0..127 (m-tile)
    const int m0 = xb * BM;
    const int n0 = yb * BM;

    f32x4 acc[4][4];
    #pragma unroll
    for (int i = 0; i < 4; ++i)
        #pragma unroll
        for (int jt = 0; jt < 4; ++jt)
            acc[i][jt] = (f32x4){0.f, 0.f, 0.f, 0.f};

    for (int kc = 0; kc < HID; kc += BK) {
        __syncthreads();
        #pragma unroll
        for (int i = 0; i < 2; ++i) {
            const int idx = tid + i * 256;          // 0..511
            const int row = idx >> 2, kq = idx & 3;
            const int go = kc + kq * 8;
            *(short8*)(Ah + row * LDK + kq * 8) =
                *(const short8*)(Ahi_g + (size_t)(m0 + row) * HID + go);
            *(short8*)(Al + row * LDK + kq * 8) =
                *(const short8*)(Alo_g + (size_t)(m0 + row) * HID + go);
            const int n = n0 + row;
            short8 vh = {0,0,0,0,0,0,0,0}, vl = {0,0,0,0,0,0,0,0};
            if (n < VOCAB) {
                vh = *(const short8*)(Bhi_g + (size_t)n * HID + go);
                vl = *(const short8*)(Blo_g + (size_t)n * HID + go);
            }
            *(short8*)(Bh + row * LDK + kq * 8) = vh;
            *(short8*)(Bl + row * LDK + kq * 8) = vl;
        }
        __syncthreads();

        short8 af_h[4], af_l[4], bf_h[4], bf_l[4];
        #pragma unroll
        for (int i = 0; i < 4; ++i) {
            const int r = wr * 64 + i * 16 + col;
            af_h[i] = *(const short8*)(Ah + r * LDK + kg * 8);
            af_l[i] = *(const short8*)(Al + r * LDK + kg * 8);
        }
        #pragma unroll
        for (int jt = 0; jt < 4; ++jt) {
            const int r = wc * 64 + jt * 16 + col;
            bf_h[jt] = *(const short8*)(Bh + r * LDK + kg * 8);
            bf_l[jt] = *(const short8*)(Bl + r * LDK + kg * 8);
        }
        #pragma unroll
        for (int i = 0; i < 4; ++i)
            #pragma unroll
            for (int jt = 0; jt < 4; ++jt) {
                acc[i][jt] = __builtin_amdgcn_mfma_f32_16x16x32_bf16(af_h[i], bf_h[jt], acc[i][jt], 0, 0, 0);
                acc[i][jt] = __builtin_amdgcn_mfma_f32_16x16x32_bf16(af_h[i], bf_l[jt], acc[i][jt], 0, 0, 0);
                acc[i][jt] = __builtin_amdgcn_mfma_f32_16x16x32_bf16(af_l[i], bf_h[jt], acc[i][jt], 0, 0, 0);
            }
    }

    #pragma unroll
    for (int i = 0; i < 4; ++i)
        #pragma unroll
        for (int jt = 0; jt < 4; ++jt)
            #pragma unroll
            for (int r = 0; r < 4; ++r) {
                const int m = m0 + wr * 64 + i * 16 + kg * 4 + r;
                const int n = n0 + wc * 64 + jt * 16 + col;
                if (n < VOCAB)
                    C[(size_t)m * VOCAB + n] = acc[i][jt][r] + bias[n];
            }
}

extern "C" void kernel_launch(void* const* d_in, const int* in_sizes, int n_in,
                              void* d_out, int out_size, void* d_ws, size_t ws_size,
                              hipStream_t stream) {
    const int*   inputs = (const int*)d_in[0];
    const float* h0     = (const float*)d_in[1];
    const float* W_ih   = (const float*)d_in[2];
    const float* W_hh   = (const float*)d_in[3];
    const float* b_ih   = (const float*)d_in[4];
    const float* b_hh   = (const float*)d_in[5];
    const float* W_out  = (const float*)d_in[6];
    const float* b_out  = (const float*)d_in[7];
    float* out = (float*)d_out;

    // workspace layout
    char* p = (char*)d_ws;
    unsigned short* ghi     = (unsigned short*)p; p += (size_t)(SEQ + 1) * HSLICE * 2;
    unsigned short* glo     = (unsigned short*)p; p += (size_t)(SEQ + 1) * HSLICE * 2;
    unsigned short* whh_hi  = (unsigned short*)p; p += (size_t)3 * HID * HID * 2;
    unsigned short* whh_lo  = (unsigned short*)p; p += (size_t)3 * HID * HID * 2;
    unsigned short* wout_hi = (unsigned short*)p; p += (size_t)VOCAB * HID * 2;
    unsigned short* wout_lo = (unsigned short*)p; p += (size_t)VOCAB * HID * 2;
    float* W_ihT            = (float*)p;          p += (size_t)VOCAB * H3 * 4;
    int* bar                = (int*)p;            p += 32768 * 4;   // 128 KB flags

    split_kernel<<<2048, 256, 0, stream>>>(W_hh, W_out, h0,
        whh_hi, whh_lo, wout_hi, wout_lo, ghi /*slice 0*/, glo /*slice 0*/);
    transpose_wih<<<dim3(VOCAB / 32, H3 / 32), 256, 0, stream>>>(W_ih, W_ihT);
    zero_barrier<<<32, 1024, 0, stream>>>(bar);

    float* hn_out = out + (size_t)SEQ * BATCH * VOCAB;
    const unsigned short* a_whh_hi = whh_hi;
    const unsigned short* a_whh_lo = whh_lo;
    const float* a_wihT = W_ihT;
    const float* a_bih = b_ih;
    const float* a_bhh = b_hh;
    const float* a_h0 = h0;
    const int* a_ids = inputs;
    unsigned short* a_ghi = ghi;
    unsigned short* a_glo = glo;
    int* a_bar = bar;
    void* kargs[] = { (void*)&a_whh_hi, (void*)&a_whh_lo, (void*)&a_wihT,
                      (void*)&a_bih, (void*)&a_bhh, (void*)&a_h0, (void*)&a_ids,
                      (void*)&a_ghi, (void*)&a_glo, (void*)&hn_out, (void*)&a_bar };
    hipLaunchCooperativeKernel((const void*)gru_persist, dim3(256), dim3(1024),
                               kargs, 0, stream);

    out_gemm_mfma<<<4096, 256, 0, stream>>>(
        ghi + HSLICE, glo + HSLICE, wout_hi, wout_lo, b_out, out);
}

// Round 14
// 1465.471 us; speedup vs baseline: 1.2844x; 1.2844x over previous
//
#include <hip/hip_runtime.h>
#include <math.h>

#define SEQ 256
#define BATCH 64
#define HID 1024
#define VOCAB 4000
#define H3 (3 * HID)
#define HSLICE (BATCH * HID)

typedef __attribute__((ext_vector_type(8))) short short8;
typedef __attribute__((ext_vector_type(4))) float f32x4;

__device__ inline unsigned short f2bf(float x) {
    unsigned int u = __builtin_bit_cast(unsigned int, x);
    unsigned int r = (u + 0x7fffu + ((u >> 16) & 1u)) >> 16;   // RNE
    return (unsigned short)r;
}
__device__ inline float bf2f(unsigned short h) {
    unsigned int u = ((unsigned int)h) << 16;
    return __builtin_bit_cast(float, u);
}

// ---------------------------------------------------------------------------
// Split f32 arrays into bf16 hi/lo pairs. h0 goes into slice 0 of the
// h-history (so the persistent kernel has no t==0 special case).
// ---------------------------------------------------------------------------
__global__ __launch_bounds__(256) void split_kernel(
    const float* __restrict__ W_hh, const float* __restrict__ W_out,
    const float* __restrict__ h0,
    unsigned short* __restrict__ whh_hi, unsigned short* __restrict__ whh_lo,
    unsigned short* __restrict__ wout_hi, unsigned short* __restrict__ wout_lo,
    unsigned short* __restrict__ h0_hi, unsigned short* __restrict__ h0_lo)
{
    const int NW = 3 * HID * HID;
    const int NO = VOCAB * HID;
    const int NH = BATCH * HID;
    const int total = NW + NO + NH;
    for (int i = blockIdx.x * blockDim.x + threadIdx.x; i < total;
         i += gridDim.x * blockDim.x) {
        const float* src; unsigned short *dh, *dl; int off;
        if (i < NW)           { src = W_hh;  dh = whh_hi;  dl = whh_lo;  off = i; }
        else if (i < NW + NO) { src = W_out; dh = wout_hi; dl = wout_lo; off = i - NW; }
        else                  { src = h0;    dh = h0_hi;   dl = h0_lo;   off = i - NW - NO; }
        float x = src[off];
        unsigned short hi = f2bf(x);
        dh[off] = hi;
        dl[off] = f2bf(x - bf2f(hi));
    }
}

// ---------------------------------------------------------------------------
// W_ih (3072 x 4000) -> W_ihT (4000 x 3072), 32x32 LDS tiles.
// ---------------------------------------------------------------------------
__global__ __launch_bounds__(256) void transpose_wih(
    const float* __restrict__ W_ih, float* __restrict__ W_ihT)
{
    __shared__ float tile[32][33];
    const int tx = threadIdx.x & 31;
    const int ty = threadIdx.x >> 5;          // 0..7
    const int r0 = blockIdx.y * 32;           // 3072-dim base
    const int c0 = blockIdx.x * 32;           // 4000-dim base
    #pragma unroll
    for (int k = 0; k < 4; ++k) {
        const int r = ty + k * 8;
        tile[r][tx] = W_ih[(size_t)(r0 + r) * VOCAB + c0 + tx];  // 4000%32==0
    }
    __syncthreads();
    #pragma unroll
    for (int k = 0; k < 4; ++k) {
        const int r = ty + k * 8;
        W_ihT[(size_t)(c0 + r) * H3 + r0 + tx] = tile[tx][r];
    }
}

__global__ void zero_barrier(int* b) {                    // 8192 ints (32 KB)
    b[blockIdx.x * 1024 + threadIdx.x] = 0;
}

// ---------------------------------------------------------------------------
// Persistent cooperative GRU — EXACT round-10 structure (best measured:
// 1105 us, 4.3 us/step). 256 blocks x 1024 threads (16 waves, 1/CU).
// Weights register-hoisted; 16-way K-split; LDS reduce; 1-thread-per-output
// epilogue with x_proj prefetch; p2p dataflow flags with agent-scope
// write-through h-stores (no fences anywhere).
// ---------------------------------------------------------------------------
__global__ __launch_bounds__(1024) void gru_persist(
    const unsigned short* __restrict__ whh_hi,
    const unsigned short* __restrict__ whh_lo,
    const float* __restrict__ W_ihT,
    const float* __restrict__ b_ih,
    const float* __restrict__ b_hh,
    const float* __restrict__ h0,
    const int* __restrict__ ids,
    unsigned short* ghi,                 // (SEQ+1) slices of 64x1024
    unsigned short* glo,
    float* hn_out,                       // d_out tail (64x1024)
    int* flag)                           // 256 flags, stride 32 ints
{
    __shared__ f32x4 red[16][3][64];     // [ksplit][gate][lane] = 48 KB

    const int tid = threadIdx.x;
    const int w   = tid >> 6;            // 0..15 (K-split)
    const int l   = tid & 63;
    const int bid = blockIdx.x;
    const int grp   = bid & 7;           // XCD (round-robin dispatch)
    const int local = bid >> 3;          // 0..31
    const int jt  = grp * 8 + (local >> 2);
    const int mt  = local & 3;
    const int j0  = jt * 16;
    const int m0  = mt * 16;
    const int col = l & 15, kg = l >> 4;

    const size_t arow   = (size_t)(m0 + col) * HID;
    const size_t brow_r = (size_t)(j0 + col) * HID;
    const size_t brow_z = (size_t)(HID + j0 + col) * HID;
    const size_t brow_n = (size_t)(2 * HID + j0 + col) * HID;
    const int kbase = w * 64 + kg * 8;

    // ---- hoist this wave's weight fragments into registers (48 VGPRs) ----
    short8 wr_h[2], wr_l[2], wz_h[2], wz_l[2], wn_h[2], wn_l[2];
    #pragma unroll
    for (int c = 0; c < 2; ++c) {
        const int ko = kbase + c * 32;
        wr_h[c] = *(const short8*)(whh_hi + brow_r + ko);
        wr_l[c] = *(const short8*)(whh_lo + brow_r + ko);
        wz_h[c] = *(const short8*)(whh_hi + brow_z + ko);
        wz_l[c] = *(const short8*)(whh_lo + brow_z + ko);
        wn_h[c] = *(const short8*)(whh_hi + brow_n + ko);
        wn_l[c] = *(const short8*)(whh_lo + brow_n + ko);
    }

    // epilogue persistent state: tid<256, 1 thread = 1 output (b, j)
    const int bi = (tid >> 4) & 15;
    const int cj = tid & 15;
    const int eb = m0 + bi, ej = j0 + cj;
    float hreg = 0.f, xr_n = 0.f, xz_n = 0.f, xn_n = 0.f;
    float bihr = 0.f, bihz = 0.f, bihn = 0.f;
    float bhhr = 0.f, bhhz = 0.f, bhhn = 0.f;
    if (tid < 256) {
        hreg = h0[(size_t)eb * HID + ej];
        bihr = b_ih[ej]; bihz = b_ih[HID + ej]; bihn = b_ih[2 * HID + ej];
        bhhr = b_hh[ej]; bhhz = b_hh[HID + ej]; bhhn = b_hh[2 * HID + ej];
        const int id0 = ids[eb * SEQ];
        const float* xrow = W_ihT + (size_t)id0 * H3;
        xr_n = xrow[ej]; xz_n = xrow[HID + ej]; xn_n = xrow[2 * HID + ej];
    }
    const int lane = ((bi & 15) >> 2) * 16 + cj;   // MFMA C-layout inverse
    const int reg  = bi & 3;

    const int myflag = (jt * 4 + mt) * 32;          // this block's flag index
    const int pollfl = ((4 * w + (l & 3)) * 4 + mt) * 32;  // lanes 0-3 poll

    for (int t = 0; t < SEQ; ++t) {
        // ---- dataflow wait: this wave's 4 producer tiles of slice t ----
        if (t > 0) {
            if (l < 4) {
                while (__hip_atomic_load(&flag[pollfl], __ATOMIC_RELAXED,
                                         __HIP_MEMORY_SCOPE_AGENT) < t)
                    __builtin_amdgcn_s_sleep(1);
            }
            asm volatile("" ::: "memory");   // no load hoisting above polls
        }

        const unsigned short* ah = ghi + (size_t)t * HSLICE;   // h_{t-1}
        const unsigned short* al = glo + (size_t)t * HSLICE;

        f32x4 accr = {0.f, 0.f, 0.f, 0.f};
        f32x4 accz = {0.f, 0.f, 0.f, 0.f};
        f32x4 accn = {0.f, 0.f, 0.f, 0.f};

        #pragma unroll
        for (int c = 0; c < 2; ++c) {
            const int ko = kbase + c * 32;
            short8 a_h = *(const short8*)(ah + arow + ko);
            short8 a_l = *(const short8*)(al + arow + ko);

            accr = __builtin_amdgcn_mfma_f32_16x16x32_bf16(a_h, wr_h[c], accr, 0, 0, 0);
            accr = __builtin_amdgcn_mfma_f32_16x16x32_bf16(a_h, wr_l[c], accr, 0, 0, 0);
            accr = __builtin_amdgcn_mfma_f32_16x16x32_bf16(a_l, wr_h[c], accr, 0, 0, 0);

            accz = __builtin_amdgcn_mfma_f32_16x16x32_bf16(a_h, wz_h[c], accz, 0, 0, 0);
            accz = __builtin_amdgcn_mfma_f32_16x16x32_bf16(a_h, wz_l[c], accz, 0, 0, 0);
            accz = __builtin_amdgcn_mfma_f32_16x16x32_bf16(a_l, wz_h[c], accz, 0, 0, 0);

            accn = __builtin_amdgcn_mfma_f32_16x16x32_bf16(a_h, wn_h[c], accn, 0, 0, 0);
            accn = __builtin_amdgcn_mfma_f32_16x16x32_bf16(a_h, wn_l[c], accn, 0, 0, 0);
            accn = __builtin_amdgcn_mfma_f32_16x16x32_bf16(a_l, wn_h[c], accn, 0, 0, 0);
        }

        red[w][0][l] = accr;
        red[w][1][l] = accz;
        red[w][2][l] = accn;
        __syncthreads();

        if (tid < 256) {
            float sr = 0.f, sz = 0.f, sn = 0.f;
            #pragma unroll
            for (int kk = 0; kk < 16; ++kk) {
                sr += ((const float*)&red[kk][0][lane])[reg];
                sz += ((const float*)&red[kk][1][lane])[reg];
                sn += ((const float*)&red[kk][2][lane])[reg];
            }
            const float xr = xr_n + bihr;
            const float xz = xz_n + bihz;
            const float xn = xn_n + bihn;
            const float rg = 1.f / (1.f + expf(-(xr + sr + bhhr)));
            const float zg = 1.f / (1.f + expf(-(xz + sz + bhhz)));
            const float ng = tanhf(xn + rg * (sn + bhhn));
            hreg = (1.f - zg) * ng + zg * hreg;

            // ---- h store: packed u32, agent-scope write-through (sc1) ----
            const unsigned short hh = f2bf(hreg);
            const unsigned short ll = f2bf(hreg - bf2f(hh));
            const unsigned int hh_n = (unsigned int)(unsigned short)
                __shfl_xor((int)hh, 1, 64);
            const unsigned int ll_n = (unsigned int)(unsigned short)
                __shfl_xor((int)ll, 1, 64);
            const size_t ho = (size_t)(t + 1) * HSLICE + (size_t)eb * HID + ej;
            if ((cj & 1) == 0) {
                const unsigned int hp = (unsigned int)hh | (hh_n << 16);
                const unsigned int lp = (unsigned int)ll | (ll_n << 16);
                __hip_atomic_store((unsigned int*)ghi + (ho >> 1), hp,
                                   __ATOMIC_RELAXED, __HIP_MEMORY_SCOPE_AGENT);
                __hip_atomic_store((unsigned int*)glo + (ho >> 1), lp,
                                   __ATOMIC_RELAXED, __HIP_MEMORY_SCOPE_AGENT);
            }

            if (t + 1 < SEQ) {                       // prefetch next x_proj row
                const int id2 = ids[eb * SEQ + t + 1];
                const float* xrow = W_ihT + (size_t)id2 * H3;
                xr_n = xrow[ej]; xz_n = xrow[HID + ej]; xn_n = xrow[2 * HID + ej];
            } else {
                hn_out[(size_t)eb * HID + ej] = hreg;
            }
        }

        // ---- publish: stores already at LLC once vmcnt drains here ----
        __syncthreads();   // drains vmcnt for all waves
        if (tid == 0) {
            __hip_atomic_store(&flag[myflag], t + 1, __ATOMIC_RELAXED,
                               __HIP_MEMORY_SCOPE_AGENT);
        }
    }
}

// ---------------------------------------------------------------------------
// Output GEMM, split-bf16 MFMA. 1D grid 4096 blocks.
// NEW vs round 10-13 GEMM:
//  (a) xb-major per-XCD order: xcd = bid&7, q = bid>>3; xb = q>>2 (m-tile),
//      yb = xcd*4 + (q&3). The 4 co-resident blocks sharing an m-panel sit
//      on the same XCD -> A panel fetched once into that XCD's L2 (4x less
//      beyond-L2 A traffic); the XCD's 4 B stripes (2 MB) stay L2-hot.
//  (b) 2-phase reg-staged double-buffer: one barrier per chunk; next chunk's
//      global loads issue right after the barrier and retire during the 48
//      MFMAs; LDS written to the other buffer after compute.
// ---------------------------------------------------------------------------
__global__ __launch_bounds__(256) void out_gemm_mfma(
    const unsigned short* __restrict__ Ahi_g,  // 16384 x 1024
    const unsigned short* __restrict__ Alo_g,
    const unsigned short* __restrict__ Bhi_g,  // 4000 x 1024
    const unsigned short* __restrict__ Blo_g,
    const float* __restrict__ bias,
    float* __restrict__ C)
{
    constexpr int BM = 128, BK = 32, LDK = 40;
    __shared__ unsigned short Ah[2][BM * LDK], Al[2][BM * LDK];
    __shared__ unsigned short Bh[2][BM * LDK], Bl[2][BM * LDK];   // 80 KB

    const int tid = threadIdx.x;
    const int l = tid & 63, w = tid >> 6;
    const int wr = w >> 1, wc = w & 1;
    const int col = l & 15, kg = l >> 4;
    const int bid = blockIdx.x;
    const int xcd = bid & 7;
    const int q   = bid >> 3;                 // 0..511
    const int xb  = q >> 2;                   // 0..127 (m-tile, xb-major)
    const int yb  = xcd * 4 + (q & 3);        // 0..31  (n-tile)
    const int m0 = xb * BM;
    const int n0 = yb * BM;

    // staging geometry: thread covers idx = tid and tid+256
    const int row0 = tid >> 2,        kq0 = tid & 3;
    const int row1 = (tid + 256) >> 2, kq1 = (tid + 256) & 3;

    f32x4 acc[4][4];
    #pragma unroll
    for (int i = 0; i < 4; ++i)
        #pragma unroll
        for (int jt = 0; jt < 4; ++jt)
            acc[i][jt] = (f32x4){0.f, 0.f, 0.f, 0.f};

    short8 pAh[2], pAl[2], pBh[2], pBl[2];
#define PREFETCH(KC)                                                          \
    {                                                                         \
        _Pragma("unroll")                                                     \
        for (int i = 0; i < 2; ++i) {                                         \
            const int row = i ? row1 : row0;                                  \
            const int kq  = i ? kq1  : kq0;                                   \
            const int go  = (KC) + kq * 8;                                    \
            pAh[i] = *(const short8*)(Ahi_g + (size_t)(m0 + row) * HID + go); \
            pAl[i] = *(const short8*)(Alo_g + (size_t)(m0 + row) * HID + go); \
            const int n = n0 + row;                                           \
            short8 vh = {0,0,0,0,0,0,0,0}, vl = {0,0,0,0,0,0,0,0};            \
            if (n < VOCAB) {                                                  \
                vh = *(const short8*)(Bhi_g + (size_t)n * HID + go);          \
                vl = *(const short8*)(Blo_g + (size_t)n * HID + go);          \
            }                                                                 \
            pBh[i] = vh; pBl[i] = vl;                                         \
        }                                                                     \
    }
#define WRITE_LDS(BUF)                                                        \
    {                                                                         \
        _Pragma("unroll")                                                     \
        for (int i = 0; i < 2; ++i) {                                         \
            const int row = i ? row1 : row0;                                  \
            const int kq  = i ? kq1  : kq0;                                   \
            *(short8*)(&Ah[BUF][row * LDK + kq * 8]) = pAh[i];                \
            *(short8*)(&Al[BUF][row * LDK + kq * 8]) = pAl[i];                \
            *(short8*)(&Bh[BUF][row * LDK + kq * 8]) = pBh[i];                \
            *(short8*)(&Bl[BUF][row * LDK + kq * 8]) = pBl[i];                \
        }                                                                     \
    }

    PREFETCH(0)
    WRITE_LDS(0)
    int cur = 0;

    for (int c = 0; c < HID / BK; ++c) {
        __syncthreads();                       // LDS[cur] ready for all
        if (c + 1 < HID / BK) PREFETCH((c + 1) * BK)   // issue early, retire
                                                       // during the MFMAs
        short8 af_h[4], af_l[4], bf_h[4], bf_l[4];
        #pragma unroll
        for (int i = 0; i < 4; ++i) {
            const int r = wr * 64 + i * 16 + col;
            af_h[i] = *(const short8*)(&Ah[cur][r * LDK + kg * 8]);
            af_l[i] = *(const short8*)(&Al[cur][r * LDK + kg * 8]);
        }
        #pragma unroll
        for (int jt = 0; jt < 4; ++jt) {
            const int r = wc * 64 + jt * 16 + col;
            bf_h[jt] = *(const short8*)(&Bh[cur][r * LDK + kg * 8]);
            bf_l[jt] = *(const short8*)(&Bl[cur][r * LDK + kg * 8]);
        }
        #pragma unroll
        for (int i = 0; i < 4; ++i)
            #pragma unroll
            for (int jt = 0; jt < 4; ++jt) {
                acc[i][jt] = __builtin_amdgcn_mfma_f32_16x16x32_bf16(af_h[i], bf_h[jt], acc[i][jt], 0, 0, 0);
                acc[i][jt] = __builtin_amdgcn_mfma_f32_16x16x32_bf16(af_h[i], bf_l[jt], acc[i][jt], 0, 0, 0);
                acc[i][jt] = __builtin_amdgcn_mfma_f32_16x16x32_bf16(af_l[i], bf_h[jt], acc[i][jt], 0, 0, 0);
            }
        if (c + 1 < HID / BK) WRITE_LDS(cur ^ 1)
        cur ^= 1;
    }
#undef PREFETCH
#undef WRITE_LDS

    #pragma unroll
    for (int i = 0; i < 4; ++i)
        #pragma unroll
        for (int jt = 0; jt < 4; ++jt)
            #pragma unroll
            for (int r = 0; r < 4; ++r) {
                const int m = m0 + wr * 64 + i * 16 + kg * 4 + r;
                const int n = n0 + wc * 64 + jt * 16 + col;
                if (n < VOCAB)
                    C[(size_t)m * VOCAB + n] = acc[i][jt][r] + bias[n];
            }
}

extern "C" void kernel_launch(void* const* d_in, const int* in_sizes, int n_in,
                              void* d_out, int out_size, void* d_ws, size_t ws_size,
                              hipStream_t stream) {
    const int*   inputs = (const int*)d_in[0];
    const float* h0     = (const float*)d_in[1];
    const float* W_ih   = (const float*)d_in[2];
    const float* W_hh   = (const float*)d_in[3];
    const float* b_ih   = (const float*)d_in[4];
    const float* b_hh   = (const float*)d_in[5];
    const float* W_out  = (const float*)d_in[6];
    const float* b_out  = (const float*)d_in[7];
    float* out = (float*)d_out;

    // workspace layout
    char* p = (char*)d_ws;
    unsigned short* ghi     = (unsigned short*)p; p += (size_t)(SEQ + 1) * HSLICE * 2;
    unsigned short* glo     = (unsigned short*)p; p += (size_t)(SEQ + 1) * HSLICE * 2;
    unsigned short* whh_hi  = (unsigned short*)p; p += (size_t)3 * HID * HID * 2;
    unsigned short* whh_lo  = (unsigned short*)p; p += (size_t)3 * HID * HID * 2;
    unsigned short* wout_hi = (unsigned short*)p; p += (size_t)VOCAB * HID * 2;
    unsigned short* wout_lo = (unsigned short*)p; p += (size_t)VOCAB * HID * 2;
    float* W_ihT            = (float*)p;          p += (size_t)VOCAB * H3 * 4;
    int* bar                = (int*)p;            p += 8192 * 4;

    split_kernel<<<2048, 256, 0, stream>>>(W_hh, W_out, h0,
        whh_hi, whh_lo, wout_hi, wout_lo, ghi /*slice 0*/, glo /*slice 0*/);
    transpose_wih<<<dim3(VOCAB / 32, H3 / 32), 256, 0, stream>>>(W_ih, W_ihT);
    zero_barrier<<<8, 1024, 0, stream>>>(bar);

    float* hn_out = out + (size_t)SEQ * BATCH * VOCAB;
    const unsigned short* a_whh_hi = whh_hi;
    const unsigned short* a_whh_lo = whh_lo;
    const float* a_wihT = W_ihT;
    const float* a_bih = b_ih;
    const float* a_bhh = b_hh;
    const float* a_h0 = h0;
    const int* a_ids = inputs;
    unsigned short* a_ghi = ghi;
    unsigned short* a_glo = glo;
    int* a_bar = bar;
    void* kargs[] = { (void*)&a_whh_hi, (void*)&a_whh_lo, (void*)&a_wihT,
                      (void*)&a_bih, (void*)&a_bhh, (void*)&a_h0, (void*)&a_ids,
                      (void*)&a_ghi, (void*)&a_glo, (void*)&hn_out, (void*)&a_bar };
    hipLaunchCooperativeKernel((const void*)gru_persist, dim3(256), dim3(1024),
                               kargs, 0, stream);

    out_gemm_mfma<<<4096, 256, 0, stream>>>(
        ghi + HSLICE, glo + HSLICE, wout_hi, wout_lo, b_out, out);
}

// Round 15
// 1447.258 us; speedup vs baseline: 1.3006x; 1.0126x over previous
//
#include <hip/hip_runtime.h>
#include <math.h>

#define SEQ 256
#define BATCH 64
#define HID 1024
#define VOCAB 4000
#define H3 (3 * HID)
#define HSLICE (BATCH * HID)

typedef __attribute__((ext_vector_type(8))) short short8;
typedef __attribute__((ext_vector_type(4))) float f32x4;

__device__ inline unsigned short f2bf(float x) {
    unsigned int u = __builtin_bit_cast(unsigned int, x);
    unsigned int r = (u + 0x7fffu + ((u >> 16) & 1u)) >> 16;   // RNE
    return (unsigned short)r;
}
__device__ inline float bf2f(unsigned short h) {
    unsigned int u = ((unsigned int)h) << 16;
    return __builtin_bit_cast(float, u);
}

// ---------------------------------------------------------------------------
// Split f32 arrays into bf16 hi/lo pairs. h0 goes into slice 0 of the
// h-history (so the persistent kernel has no t==0 special case).
// ---------------------------------------------------------------------------
__global__ __launch_bounds__(256) void split_kernel(
    const float* __restrict__ W_hh, const float* __restrict__ W_out,
    const float* __restrict__ h0,
    unsigned short* __restrict__ whh_hi, unsigned short* __restrict__ whh_lo,
    unsigned short* __restrict__ wout_hi, unsigned short* __restrict__ wout_lo,
    unsigned short* __restrict__ h0_hi, unsigned short* __restrict__ h0_lo)
{
    const int NW = 3 * HID * HID;
    const int NO = VOCAB * HID;
    const int NH = BATCH * HID;
    const int total = NW + NO + NH;
    for (int i = blockIdx.x * blockDim.x + threadIdx.x; i < total;
         i += gridDim.x * blockDim.x) {
        const float* src; unsigned short *dh, *dl; int off;
        if (i < NW)           { src = W_hh;  dh = whh_hi;  dl = whh_lo;  off = i; }
        else if (i < NW + NO) { src = W_out; dh = wout_hi; dl = wout_lo; off = i - NW; }
        else                  { src = h0;    dh = h0_hi;   dl = h0_lo;   off = i - NW - NO; }
        float x = src[off];
        unsigned short hi = f2bf(x);
        dh[off] = hi;
        dl[off] = f2bf(x - bf2f(hi));
    }
}

// ---------------------------------------------------------------------------
// W_ih (3072 x 4000) -> W_ihT (4000 x 3072), 32x32 LDS tiles.
// ---------------------------------------------------------------------------
__global__ __launch_bounds__(256) void transpose_wih(
    const float* __restrict__ W_ih, float* __restrict__ W_ihT)
{
    __shared__ float tile[32][33];
    const int tx = threadIdx.x & 31;
    const int ty = threadIdx.x >> 5;          // 0..7
    const int r0 = blockIdx.y * 32;           // 3072-dim base
    const int c0 = blockIdx.x * 32;           // 4000-dim base
    #pragma unroll
    for (int k = 0; k < 4; ++k) {
        const int r = ty + k * 8;
        tile[r][tx] = W_ih[(size_t)(r0 + r) * VOCAB + c0 + tx];  // 4000%32==0
    }
    __syncthreads();
    #pragma unroll
    for (int k = 0; k < 4; ++k) {
        const int r = ty + k * 8;
        W_ihT[(size_t)(c0 + r) * H3 + r0 + tx] = tile[tx][r];
    }
}

__global__ void zero_barrier(int* b) {                    // 8192 ints (32 KB)
    b[blockIdx.x * 1024 + threadIdx.x] = 0;
}

// ---------------------------------------------------------------------------
// Persistent cooperative GRU: round-10 LLC protocol (UNCHANGED: one flag per
// block, 4-flag polls, agent-scope write-through h-stores, no fences) with
// the intra-block barrier #2 ELIMINATED:
//   - red[] parity-double-buffered (pad 65 -> bank-rotating reduce reads).
//     t+2 reuse is ordered transitively: epilogue waves reach barrier#1(t+1)
//     only after epilogue(t) finished reading red[par].
//   - last-arriver publish: each epilogue wave drains its OWN vmcnt(0) (its
//     WT stores then at LLC), bumps an LDS counter; the 4th wave stores the
//     block flag. Per-wave drain -> LDS atomic -> flag is transitively
//     ordered; flag/poll LLC traffic is byte-identical to round 10.
//   - waves 4-15 skip the publish entirely: straight from barrier#1 to
//     polling/loading t+1, pre-staging their LLC h-loads under the publish.
//   - x_proj prefetch issues after the counter bump (outside the drain set).
// ---------------------------------------------------------------------------
__global__ __launch_bounds__(1024) void gru_persist(
    const unsigned short* __restrict__ whh_hi,
    const unsigned short* __restrict__ whh_lo,
    const float* __restrict__ W_ihT,
    const float* __restrict__ b_ih,
    const float* __restrict__ b_hh,
    const float* __restrict__ h0,
    const int* __restrict__ ids,
    unsigned short* ghi,                 // (SEQ+1) slices of 64x1024
    unsigned short* glo,
    float* hn_out,                       // d_out tail (64x1024)
    int* flag)                           // 256 flags, stride 32 ints
{
    __shared__ f32x4 red[2][16][3][65];  // parity dbuf + pad, ~99.8 KB
    __shared__ int epi_cnt;              // monotone, 4 per step

    const int tid = threadIdx.x;
    const int w   = tid >> 6;            // 0..15 (K-split)
    const int l   = tid & 63;
    const int bid = blockIdx.x;
    const int grp   = bid & 7;           // XCD (round-robin dispatch)
    const int local = bid >> 3;          // 0..31
    const int jt  = grp * 8 + (local >> 2);
    const int mt  = local & 3;
    const int j0  = jt * 16;
    const int m0  = mt * 16;
    const int col = l & 15, kg = l >> 4;

    const size_t arow   = (size_t)(m0 + col) * HID;
    const size_t brow_r = (size_t)(j0 + col) * HID;
    const size_t brow_z = (size_t)(HID + j0 + col) * HID;
    const size_t brow_n = (size_t)(2 * HID + j0 + col) * HID;
    const int kbase = w * 64 + kg * 8;

    // ---- hoist this wave's weight fragments into registers (48 VGPRs) ----
    short8 wr_h[2], wr_l[2], wz_h[2], wz_l[2], wn_h[2], wn_l[2];
    #pragma unroll
    for (int c = 0; c < 2; ++c) {
        const int ko = kbase + c * 32;
        wr_h[c] = *(const short8*)(whh_hi + brow_r + ko);
        wr_l[c] = *(const short8*)(whh_lo + brow_r + ko);
        wz_h[c] = *(const short8*)(whh_hi + brow_z + ko);
        wz_l[c] = *(const short8*)(whh_lo + brow_z + ko);
        wn_h[c] = *(const short8*)(whh_hi + brow_n + ko);
        wn_l[c] = *(const short8*)(whh_lo + brow_n + ko);
    }

    // epilogue persistent state: tid<256, 1 thread = 1 output (b, j)
    const int bi = (tid >> 4) & 15;
    const int cj = tid & 15;
    const int eb = m0 + bi, ej = j0 + cj;
    float hreg = 0.f, xr_n = 0.f, xz_n = 0.f, xn_n = 0.f;
    float bihr = 0.f, bihz = 0.f, bihn = 0.f;
    float bhhr = 0.f, bhhz = 0.f, bhhn = 0.f;
    if (tid < 256) {
        hreg = h0[(size_t)eb * HID + ej];
        bihr = b_ih[ej]; bihz = b_ih[HID + ej]; bihn = b_ih[2 * HID + ej];
        bhhr = b_hh[ej]; bhhz = b_hh[HID + ej]; bhhn = b_hh[2 * HID + ej];
        const int id0 = ids[eb * SEQ];
        const float* xrow = W_ihT + (size_t)id0 * H3;
        xr_n = xrow[ej]; xz_n = xrow[HID + ej]; xn_n = xrow[2 * HID + ej];
    }
    const int lane = ((bi & 15) >> 2) * 16 + cj;   // MFMA C-layout inverse
    const int reg  = bi & 3;

    const int myflag = (jt * 4 + mt) * 32;          // this block's flag index
    const int pollfl = ((4 * w + (l & 3)) * 4 + mt) * 32;  // lanes 0-3 poll

    if (tid == 0) epi_cnt = 0;
    __syncthreads();

    for (int t = 0; t < SEQ; ++t) {
        // ---- dataflow wait: this wave's 4 producer tiles of slice t ----
        if (t > 0) {
            if (l < 4) {
                while (__hip_atomic_load(&flag[pollfl], __ATOMIC_RELAXED,
                                         __HIP_MEMORY_SCOPE_AGENT) < t)
                    __builtin_amdgcn_s_sleep(1);
            }
            asm volatile("" ::: "memory");   // no load hoisting above polls
        }

        const unsigned short* ah = ghi + (size_t)t * HSLICE;   // h_{t-1}
        const unsigned short* al = glo + (size_t)t * HSLICE;

        f32x4 accr = {0.f, 0.f, 0.f, 0.f};
        f32x4 accz = {0.f, 0.f, 0.f, 0.f};
        f32x4 accn = {0.f, 0.f, 0.f, 0.f};

        #pragma unroll
        for (int c = 0; c < 2; ++c) {
            const int ko = kbase + c * 32;
            short8 a_h = *(const short8*)(ah + arow + ko);
            short8 a_l = *(const short8*)(al + arow + ko);

            accr = __builtin_amdgcn_mfma_f32_16x16x32_bf16(a_h, wr_h[c], accr, 0, 0, 0);
            accr = __builtin_amdgcn_mfma_f32_16x16x32_bf16(a_h, wr_l[c], accr, 0, 0, 0);
            accr = __builtin_amdgcn_mfma_f32_16x16x32_bf16(a_l, wr_h[c], accr, 0, 0, 0);

            accz = __builtin_amdgcn_mfma_f32_16x16x32_bf16(a_h, wz_h[c], accz, 0, 0, 0);
            accz = __builtin_amdgcn_mfma_f32_16x16x32_bf16(a_h, wz_l[c], accz, 0, 0, 0);
            accz = __builtin_amdgcn_mfma_f32_16x16x32_bf16(a_l, wz_h[c], accz, 0, 0, 0);

            accn = __builtin_amdgcn_mfma_f32_16x16x32_bf16(a_h, wn_h[c], accn, 0, 0, 0);
            accn = __builtin_amdgcn_mfma_f32_16x16x32_bf16(a_h, wn_l[c], accn, 0, 0, 0);
            accn = __builtin_amdgcn_mfma_f32_16x16x32_bf16(a_l, wn_h[c], accn, 0, 0, 0);
        }

        const int par = t & 1;
        red[par][w][0][l] = accr;
        red[par][w][1][l] = accz;
        red[par][w][2][l] = accn;
        __syncthreads();                 // barrier #1 (the only one)

        if (tid < 256) {
            float sr = 0.f, sz = 0.f, sn = 0.f;
            #pragma unroll
            for (int kk = 0; kk < 16; ++kk) {
                sr += ((const float*)&red[par][kk][0][lane])[reg];
                sz += ((const float*)&red[par][kk][1][lane])[reg];
                sn += ((const float*)&red[par][kk][2][lane])[reg];
            }
            const float xr = xr_n + bihr;
            const float xz = xz_n + bihz;
            const float xn = xn_n + bihn;
            const float rg = 1.f / (1.f + expf(-(xr + sr + bhhr)));
            const float zg = 1.f / (1.f + expf(-(xz + sz + bhhz)));
            const float ng = tanhf(xn + rg * (sn + bhhn));
            hreg = (1.f - zg) * ng + zg * hreg;

            // ---- h store: packed u32, agent-scope write-through (sc1) ----
            const unsigned short hh = f2bf(hreg);
            const unsigned short ll = f2bf(hreg - bf2f(hh));
            const unsigned int hh_n = (unsigned int)(unsigned short)
                __shfl_xor((int)hh, 1, 64);
            const unsigned int ll_n = (unsigned int)(unsigned short)
                __shfl_xor((int)ll, 1, 64);
            const size_t ho = (size_t)(t + 1) * HSLICE + (size_t)eb * HID + ej;
            if ((cj & 1) == 0) {
                const unsigned int hp = (unsigned int)hh | (hh_n << 16);
                const unsigned int lp = (unsigned int)ll | (ll_n << 16);
                __hip_atomic_store((unsigned int*)ghi + (ho >> 1), hp,
                                   __ATOMIC_RELAXED, __HIP_MEMORY_SCOPE_AGENT);
                __hip_atomic_store((unsigned int*)glo + (ho >> 1), lp,
                                   __ATOMIC_RELAXED, __HIP_MEMORY_SCOPE_AGENT);
            }

            // per-wave drain -> LDS last-arriver publishes the block flag
            asm volatile("s_waitcnt vmcnt(0)" ::: "memory");
            if (l == 0) {
                const int old = atomicAdd(&epi_cnt, 1);
                if (old == 4 * t + 3) {
                    __hip_atomic_store(&flag[myflag], t + 1, __ATOMIC_RELAXED,
                                       __HIP_MEMORY_SCOPE_AGENT);
                }
            }

            // prefetch next x_proj row AFTER publish (outside drain set)
            if (t + 1 < SEQ) {
                const int id2 = ids[eb * SEQ + t + 1];
                const float* xrow = W_ihT + (size_t)id2 * H3;
                xr_n = xrow[ej]; xz_n = xrow[HID + ej]; xn_n = xrow[2 * HID + ej];
            } else {
                hn_out[(size_t)eb * HID + ej] = hreg;
            }
        }
        // no barrier #2: waves 4-15 proceed straight to polling t+1;
        // red[] reuse at t+2 is ordered through barrier#1(t+1).
    }
}

// ---------------------------------------------------------------------------
// Output GEMM, split-bf16 MFMA — round-14 version (frozen):
// xb-major per-XCD order + 2-phase reg-staged double-buffer.
// ---------------------------------------------------------------------------
__global__ __launch_bounds__(256) void out_gemm_mfma(
    const unsigned short* __restrict__ Ahi_g,  // 16384 x 1024
    const unsigned short* __restrict__ Alo_g,
    const unsigned short* __restrict__ Bhi_g,  // 4000 x 1024
    const unsigned short* __restrict__ Blo_g,
    const float* __restrict__ bias,
    float* __restrict__ C)
{
    constexpr int BM = 128, BK = 32, LDK = 40;
    __shared__ unsigned short Ah[2][BM * LDK], Al[2][BM * LDK];
    __shared__ unsigned short Bh[2][BM * LDK], Bl[2][BM * LDK];   // 80 KB

    const int tid = threadIdx.x;
    const int l = tid & 63, w = tid >> 6;
    const int wr = w >> 1, wc = w & 1;
    const int col = l & 15, kg = l >> 4;
    const int bid = blockIdx.x;
    const int xcd = bid & 7;
    const int q   = bid >> 3;                 // 0..511
    const int xb  = q >> 2;                   // 0..127 (m-tile, xb-major)
    const int yb  = xcd * 4 + (q & 3);        // 0..31  (n-tile)
    const int m0 = xb * BM;
    const int n0 = yb * BM;

    const int row0 = tid >> 2,        kq0 = tid & 3;
    const int row1 = (tid + 256) >> 2, kq1 = (tid + 256) & 3;

    f32x4 acc[4][4];
    #pragma unroll
    for (int i = 0; i < 4; ++i)
        #pragma unroll
        for (int jt = 0; jt < 4; ++jt)
            acc[i][jt] = (f32x4){0.f, 0.f, 0.f, 0.f};

    short8 pAh[2], pAl[2], pBh[2], pBl[2];
#define PREFETCH(KC)                                                          \
    {                                                                         \
        _Pragma("unroll")                                                     \
        for (int i = 0; i < 2; ++i) {                                         \
            const int row = i ? row1 : row0;                                  \
            const int kq  = i ? kq1  : kq0;                                   \
            const int go  = (KC) + kq * 8;                                    \
            pAh[i] = *(const short8*)(Ahi_g + (size_t)(m0 + row) * HID + go); \
            pAl[i] = *(const short8*)(Alo_g + (size_t)(m0 + row) * HID + go); \
            const int n = n0 + row;                                           \
            short8 vh = {0,0,0,0,0,0,0,0}, vl = {0,0,0,0,0,0,0,0};            \
            if (n < VOCAB) {                                                  \
                vh = *(const short8*)(Bhi_g + (size_t)n * HID + go);          \
                vl = *(const short8*)(Blo_g + (size_t)n * HID + go);          \
            }                                                                 \
            pBh[i] = vh; pBl[i] = vl;                                         \
        }                                                                     \
    }
#define WRITE_LDS(BUF)                                                        \
    {                                                                         \
        _Pragma("unroll")                                                     \
        for (int i = 0; i < 2; ++i) {                                         \
            const int row = i ? row1 : row0;                                  \
            const int kq  = i ? kq1  : kq0;                                   \
            *(short8*)(&Ah[BUF][row * LDK + kq * 8]) = pAh[i];                \
            *(short8*)(&Al[BUF][row * LDK + kq * 8]) = pAl[i];                \
            *(short8*)(&Bh[BUF][row * LDK + kq * 8]) = pBh[i];                \
            *(short8*)(&Bl[BUF][row * LDK + kq * 8]) = pBl[i];                \
        }                                                                     \
    }

    PREFETCH(0)
    WRITE_LDS(0)
    int cur = 0;

    for (int c = 0; c < HID / BK; ++c) {
        __syncthreads();
        if (c + 1 < HID / BK) PREFETCH((c + 1) * BK)

        short8 af_h[4], af_l[4], bf_h[4], bf_l[4];
        #pragma unroll
        for (int i = 0; i < 4; ++i) {
            const int r = wr * 64 + i * 16 + col;
            af_h[i] = *(const short8*)(&Ah[cur][r * LDK + kg * 8]);
            af_l[i] = *(const short8*)(&Al[cur][r * LDK + kg * 8]);
        }
        #pragma unroll
        for (int jt = 0; jt < 4; ++jt) {
            const int r = wc * 64 + jt * 16 + col;
            bf_h[jt] = *(const short8*)(&Bh[cur][r * LDK + kg * 8]);
            bf_l[jt] = *(const short8*)(&Bl[cur][r * LDK + kg * 8]);
        }
        #pragma unroll
        for (int i = 0; i < 4; ++i)
            #pragma unroll
            for (int jt = 0; jt < 4; ++jt) {
                acc[i][jt] = __builtin_amdgcn_mfma_f32_16x16x32_bf16(af_h[i], bf_h[jt], acc[i][jt], 0, 0, 0);
                acc[i][jt] = __builtin_amdgcn_mfma_f32_16x16x32_bf16(af_h[i], bf_l[jt], acc[i][jt], 0, 0, 0);
                acc[i][jt] = __builtin_amdgcn_mfma_f32_16x16x32_bf16(af_l[i], bf_h[jt], acc[i][jt], 0, 0, 0);
            }
        if (c + 1 < HID / BK) WRITE_LDS(cur ^ 1)
        cur ^= 1;
    }
#undef PREFETCH
#undef WRITE_LDS

    #pragma unroll
    for (int i = 0; i < 4; ++i)
        #pragma unroll
        for (int jt = 0; jt < 4; ++jt)
            #pragma unroll
            for (int r = 0; r < 4; ++r) {
                const int m = m0 + wr * 64 + i * 16 + kg * 4 + r;
                const int n = n0 + wc * 64 + jt * 16 + col;
                if (n < VOCAB)
                    C[(size_t)m * VOCAB + n] = acc[i][jt][r] + bias[n];
            }
}

extern "C" void kernel_launch(void* const* d_in, const int* in_sizes, int n_in,
                              void* d_out, int out_size, void* d_ws, size_t ws_size,
                              hipStream_t stream) {
    const int*   inputs = (const int*)d_in[0];
    const float* h0     = (const float*)d_in[1];
    const float* W_ih   = (const float*)d_in[2];
    const float* W_hh   = (const float*)d_in[3];
    const float* b_ih   = (const float*)d_in[4];
    const float* b_hh   = (const float*)d_in[5];
    const float* W_out  = (const float*)d_in[6];
    const float* b_out  = (const float*)d_in[7];
    float* out = (float*)d_out;

    // workspace layout
    char* p = (char*)d_ws;
    unsigned short* ghi     = (unsigned short*)p; p += (size_t)(SEQ + 1) * HSLICE * 2;
    unsigned short* glo     = (unsigned short*)p; p += (size_t)(SEQ + 1) * HSLICE * 2;
    unsigned short* whh_hi  = (unsigned short*)p; p += (size_t)3 * HID * HID * 2;
    unsigned short* whh_lo  = (unsigned short*)p; p += (size_t)3 * HID * HID * 2;
    unsigned short* wout_hi = (unsigned short*)p; p += (size_t)VOCAB * HID * 2;
    unsigned short* wout_lo = (unsigned short*)p; p += (size_t)VOCAB * HID * 2;
    float* W_ihT            = (float*)p;          p += (size_t)VOCAB * H3 * 4;
    int* bar                = (int*)p;            p += 8192 * 4;

    split_kernel<<<2048, 256, 0, stream>>>(W_hh, W_out, h0,
        whh_hi, whh_lo, wout_hi, wout_lo, ghi /*slice 0*/, glo /*slice 0*/);
    transpose_wih<<<dim3(VOCAB / 32, H3 / 32), 256, 0, stream>>>(W_ih, W_ihT);
    zero_barrier<<<8, 1024, 0, stream>>>(bar);

    float* hn_out = out + (size_t)SEQ * BATCH * VOCAB;
    const unsigned short* a_whh_hi = whh_hi;
    const unsigned short* a_whh_lo = whh_lo;
    const float* a_wihT = W_ihT;
    const float* a_bih = b_ih;
    const float* a_bhh = b_hh;
    const float* a_h0 = h0;
    const int* a_ids = inputs;
    unsigned short* a_ghi = ghi;
    unsigned short* a_glo = glo;
    int* a_bar = bar;
    void* kargs[] = { (void*)&a_whh_hi, (void*)&a_whh_lo, (void*)&a_wihT,
                      (void*)&a_bih, (void*)&a_bhh, (void*)&a_h0, (void*)&a_ids,
                      (void*)&a_ghi, (void*)&a_glo, (void*)&hn_out, (void*)&a_bar };
    hipLaunchCooperativeKernel((const void*)gru_persist, dim3(256), dim3(1024),
                               kargs, 0, stream);

    out_gemm_mfma<<<4096, 256, 0, stream>>>(
        ghi + HSLICE, glo + HSLICE, wout_hi, wout_lo, b_out, out);
}